// Round 2
// baseline (372.022 us; speedup 1.0000x reference)
//
#include <hip/hip_runtime.h>

// StandGCN2: 2-layer GCN, N=100000 nodes, E=600000 edges, 128->128(relu)->64.
// Dtype-adaptive: a probe kernel detects whether float inputs are fp32 or bf16
// (mode flag in ws), inputs are canonicalized to bf16, internals run bf16 MFMA
// with fp32 accumulation, output written as fp32 or bf16 per mode.
// Pipeline: probe -> convert -> CSR-by-dst build -> GEMM1 -> agg1(+b,relu)
//           -> GEMM2 -> agg2(+b) -> d_out.

typedef unsigned short u16;
typedef unsigned int u32;
typedef __attribute__((ext_vector_type(8))) short bf16x8;
typedef __attribute__((ext_vector_type(4))) float f32x4;

__device__ __forceinline__ float b2f(u16 s) {
  return __uint_as_float(((u32)s) << 16);
}
__device__ __forceinline__ u16 f2b(float f) {
  u32 u = __float_as_uint(f);
  u32 r = (u + 0x7FFFu + ((u >> 16) & 1u)) >> 16;
  return (u16)r;
}

// ---------------- dtype probe ----------------
// Genuine bf16 weights (~N(0,1/sqrt(128))) have exponent field in [100,130]
// nearly always. fp32 data viewed as u16s: half the u16s are random mantissa
// bits (~12% pass) -> overall ~54%. Threshold at ~79%.

__global__ __launch_bounds__(256) void probe_k(const u16* __restrict__ w,
                                               int* __restrict__ mode, int nu16) {
  __shared__ int cnt_s;
  if (threadIdx.x == 0) cnt_s = 0;
  __syncthreads();
  int c = 0;
  for (int i = threadIdx.x; i < nu16; i += 256) {
    u32 e = (w[i] >> 7) & 0xFFu;
    if (e >= 100u && e <= 130u) c++;
  }
  atomicAdd(&cnt_s, c);
  __syncthreads();
  if (threadIdx.x == 0) *mode = (cnt_s < (nu16 * 13) / 16) ? 1 : 0;  // 1 = fp32
}

__global__ __launch_bounds__(256) void cvt_k(const void* __restrict__ in,
                                             u16* __restrict__ out, int n,
                                             const int* __restrict__ mode) {
  int m = *mode;
  int i = blockIdx.x * 256 + threadIdx.x;
  if (i >= n) return;
  out[i] = m ? f2b(((const float*)in)[i]) : ((const u16*)in)[i];
}

// ---------------- CSR build ----------------

__global__ __launch_bounds__(256) void count_k(const int* __restrict__ dst,
                                               int* __restrict__ cnt, int E) {
  int e = blockIdx.x * 256 + threadIdx.x;
  if (e < E) atomicAdd(&cnt[dst[e]], 1);
}

__global__ __launch_bounds__(256) void dinv_k(const int* __restrict__ cnt,
                                              float* __restrict__ dinv, int n) {
  int i = blockIdx.x * 256 + threadIdx.x;
  if (i < n) dinv[i] = rsqrtf((float)cnt[i] + 1.0f);  // +1 self-loop
}

__global__ __launch_bounds__(256) void scan1(const int* __restrict__ cnt,
                                             int* __restrict__ offs,
                                             int* __restrict__ bsum, int np) {
  __shared__ int lds[256];
  int t = threadIdx.x;
  int i = blockIdx.x * 256 + t;
  int v = cnt[i];
  lds[t] = v;
  __syncthreads();
#pragma unroll
  for (int off = 1; off < 256; off <<= 1) {
    int add = (t >= off) ? lds[t - off] : 0;
    __syncthreads();
    lds[t] += add;
    __syncthreads();
  }
  offs[i] = lds[t] - v;  // exclusive within block
  if (t == 0) bsum[blockIdx.x] = lds[255];
}

__global__ __launch_bounds__(512) void scan2(const int* __restrict__ bsum,
                                             int* __restrict__ bscan, int nb) {
  __shared__ int lds[512];
  int t = threadIdx.x;
  int v = (t < nb) ? bsum[t] : 0;
  lds[t] = v;
  __syncthreads();
#pragma unroll
  for (int off = 1; off < 512; off <<= 1) {
    int add = (t >= off) ? lds[t - off] : 0;
    __syncthreads();
    lds[t] += add;
    __syncthreads();
  }
  bscan[t] = lds[t] - v;
}

__global__ __launch_bounds__(256) void scan3(int* __restrict__ offs,
                                             const int* __restrict__ bscan,
                                             int* __restrict__ cursor, int np) {
  int i = blockIdx.x * 256 + threadIdx.x;
  int o = offs[i] + bscan[blockIdx.x];
  offs[i] = o;
  cursor[i] = o;
}

__global__ __launch_bounds__(256) void fill_k(const int* __restrict__ src,
                                              const int* __restrict__ dst,
                                              int* __restrict__ cursor,
                                              int* __restrict__ srcs_sorted, int E) {
  int e = blockIdx.x * 256 + threadIdx.x;
  if (e < E) {
    int p = atomicAdd(&cursor[dst[e]], 1);
    srcs_sorted[p] = src[e];
  }
}

// ---------------- GEMM (bf16 MFMA), K=128 fixed, NCOLS in {128,64} ----------------
// W staged transposed in LDS: Wt[n][k], pitch 136 shorts (=17*16B).
// Layouts (learn_hip m89/m91): A-frag A[m=lane&15][k=(lane>>4)*8+j],
// B-frag B[k=(lane>>4)*8+j][n=lane&15], C/D col=lane&15 row=(lane>>4)*4+reg.

template <int NCOLS>
__global__ __launch_bounds__(256) void gemm_bf16(const u16* __restrict__ A,
                                                 const u16* __restrict__ W,
                                                 u16* __restrict__ out, int M) {
  constexpr int NT = NCOLS / 16;
  __shared__ __align__(16) u16 Wt[NCOLS * 136];
  __shared__ __align__(16) u16 As[64 * 136];
  const int tid = threadIdx.x;

  for (int idx = tid; idx < 128 * NCOLS; idx += 256) {
    int n = idx % NCOLS;
    int k = idx / NCOLS;
    Wt[n * 136 + k] = W[k * NCOLS + n];
  }
  __syncthreads();

  const int wv = tid >> 6, lane = tid & 63, lr = lane & 15, lq = lane >> 4;
  const int ntiles = (M + 63) >> 6;

  for (int t = blockIdx.x; t < ntiles; t += gridDim.x) {
    const int r0 = t * 64;
    __syncthreads();
    for (int idx = tid; idx < 64 * 16; idx += 256) {
      int row = idx >> 4, c = idx & 15;
      uint4 v = make_uint4(0u, 0u, 0u, 0u);
      if (r0 + row < M) v = *(const uint4*)&A[(size_t)(r0 + row) * 128 + c * 8];
      *(uint4*)&As[row * 136 + c * 8] = v;
    }
    __syncthreads();

    bf16x8 a[4];
#pragma unroll
    for (int s = 0; s < 4; ++s)
      a[s] = *(const bf16x8*)&As[(wv * 16 + lr) * 136 + s * 32 + lq * 8];

#pragma unroll
    for (int nt = 0; nt < NT; ++nt) {
      f32x4 acc = {0.f, 0.f, 0.f, 0.f};
#pragma unroll
      for (int s = 0; s < 4; ++s) {
        bf16x8 b = *(const bf16x8*)&Wt[(nt * 16 + lr) * 136 + s * 32 + lq * 8];
        acc = __builtin_amdgcn_mfma_f32_16x16x32_bf16(a[s], b, acc, 0, 0, 0);
      }
#pragma unroll
      for (int r = 0; r < 4; ++r) {
        int row = r0 + wv * 16 + lq * 4 + r;
        if (row < M) out[(size_t)row * NCOLS + nt * 16 + lr] = f2b(acc[r]);
      }
    }
  }
}

// ---------------- Aggregation (one wave per node, fp32 accum) ----------------

__global__ __launch_bounds__(256) void agg1(const u16* __restrict__ h,
                                            const int* __restrict__ srcs,
                                            const int* __restrict__ offs,
                                            const int* __restrict__ cnt,
                                            const float* __restrict__ dinv,
                                            const u16* __restrict__ b1,
                                            u16* __restrict__ h1, int n) {
  int i = blockIdx.x * 4 + (threadIdx.x >> 6);
  if (i >= n) return;
  int lane = threadIdx.x & 63;
  int f = lane * 2;
  float di = dinv[i];
  int start = offs[i], c = cnt[i];

  u32 sv = *(const u32*)&h[(size_t)i * 128 + f];
  float ax = b2f((u16)(sv & 0xFFFF)) * di;
  float ay = b2f((u16)(sv >> 16)) * di;

  for (int e = 0; e < c; ++e) {
    int s = srcs[start + e];
    float ds = dinv[s];
    u32 v = *(const u32*)&h[(size_t)s * 128 + f];
    ax += b2f((u16)(v & 0xFFFF)) * ds;
    ay += b2f((u16)(v >> 16)) * ds;
  }
  u32 bv = *(const u32*)&b1[f];
  float o0 = fmaxf(ax * di + b2f((u16)(bv & 0xFFFF)), 0.f);
  float o1 = fmaxf(ay * di + b2f((u16)(bv >> 16)), 0.f);
  *(u32*)&h1[(size_t)i * 128 + f] = (u32)f2b(o0) | ((u32)f2b(o1) << 16);
}

__global__ __launch_bounds__(256) void agg2(const u16* __restrict__ h2,
                                            const int* __restrict__ srcs,
                                            const int* __restrict__ offs,
                                            const int* __restrict__ cnt,
                                            const float* __restrict__ dinv,
                                            const u16* __restrict__ b2,
                                            void* __restrict__ outv, int n,
                                            const int* __restrict__ mode) {
  int i = blockIdx.x * 4 + (threadIdx.x >> 6);
  if (i >= n) return;
  int lane = threadIdx.x & 63;
  float di = dinv[i];
  int start = offs[i], c = cnt[i];

  float acc = b2f(h2[(size_t)i * 64 + lane]) * di;
  for (int e = 0; e < c; ++e) {
    int s = srcs[start + e];
    acc += b2f(h2[(size_t)s * 64 + lane]) * dinv[s];
  }
  float o = acc * di + b2f(b2[lane]);
  size_t idx = (size_t)i * 64 + lane;
  if (*mode) ((float*)outv)[idx] = o;
  else       ((u16*)outv)[idx] = f2b(o);
}

// ---------------- launch ----------------

extern "C" void kernel_launch(void* const* d_in, const int* in_sizes, int n_in,
                              void* d_out, int out_size, void* d_ws, size_t ws_size,
                              hipStream_t stream) {
  const void* x_raw  = d_in[0];
  const int*  ei     = (const int*)d_in[1];
  const void* W1_raw = d_in[2];
  const void* b1_raw = d_in[3];
  const void* W2_raw = d_in[4];
  const void* b2_raw = d_in[5];

  const int N = in_sizes[0] / 128;
  const int E = in_sizes[1] / 2;
  const int* srcA = ei;      // edge_index[0]
  const int* dstA = ei + E;  // edge_index[1]

  const int NP = ((N + 255) / 256) * 256;
  const int NB = NP / 256;

  char* ws = (char*)d_ws;
  size_t off = 0;
  auto alloc = [&](size_t bytes) -> void* {
    void* p = ws + off;
    off = (off + bytes + 255) & ~(size_t)255;
    return p;
  };
  int*   mode   = (int*)alloc(4);
  int*   cnt    = (int*)alloc((size_t)NP * 4);
  float* dinv   = (float*)alloc((size_t)NP * 4);
  int*   offs   = (int*)alloc((size_t)NP * 4);
  int*   cursor = (int*)alloc((size_t)NP * 4);
  int*   bsum   = (int*)alloc(512 * 4);
  int*   bscan  = (int*)alloc(512 * 4);
  int*   srcs   = (int*)alloc((size_t)E * 4);
  u16*   xb     = (u16*)alloc((size_t)N * 128 * 2);
  u16*   W1b    = (u16*)alloc((size_t)128 * 128 * 2);
  u16*   b1b    = (u16*)alloc(128 * 2);
  u16*   W2b    = (u16*)alloc((size_t)128 * 64 * 2);
  u16*   b2b    = (u16*)alloc(64 * 2);
  u16*   h      = (u16*)alloc((size_t)N * 128 * 2);
  u16*   h1     = (u16*)alloc((size_t)N * 128 * 2);
  u16*   h2     = (u16*)alloc((size_t)N * 64 * 2);

  hipMemsetAsync(cnt, 0, (size_t)NP * 4, stream);

  // dtype probe on W1 (16384 elements; reading 16384 u16s is safe either way)
  probe_k<<<1, 256, 0, stream>>>((const u16*)W1_raw, mode, in_sizes[2]);

  // canonicalize to bf16
  const int nx = N * 128;
  cvt_k<<<(nx + 255) / 256, 256, 0, stream>>>(x_raw, xb, nx, mode);
  cvt_k<<<(128 * 128 + 255) / 256, 256, 0, stream>>>(W1_raw, W1b, 128 * 128, mode);
  cvt_k<<<1, 256, 0, stream>>>(b1_raw, b1b, 128, mode);
  cvt_k<<<(128 * 64 + 255) / 256, 256, 0, stream>>>(W2_raw, W2b, 128 * 64, mode);
  cvt_k<<<1, 256, 0, stream>>>(b2_raw, b2b, 64, mode);

  const int eb = (E + 255) / 256;
  count_k<<<eb, 256, 0, stream>>>(dstA, cnt, E);
  dinv_k<<<NB, 256, 0, stream>>>(cnt, dinv, N);
  scan1<<<NB, 256, 0, stream>>>(cnt, offs, bsum, NP);
  scan2<<<1, 512, 0, stream>>>(bsum, bscan, NB);
  scan3<<<NB, 256, 0, stream>>>(offs, bscan, cursor, NP);
  fill_k<<<eb, 256, 0, stream>>>(srcA, dstA, cursor, srcs, E);

  gemm_bf16<128><<<512, 256, 0, stream>>>(xb, W1b, h, N);
  agg1<<<(N + 3) / 4, 256, 0, stream>>>(h, srcs, offs, cnt, dinv, b1b, h1, N);
  gemm_bf16<64><<<512, 256, 0, stream>>>(h1, W2b, h2, N);
  agg2<<<(N + 3) / 4, 256, 0, stream>>>(h2, srcs, offs, cnt, dinv, b2b, d_out, N, mode);
}

// Round 3
// 275.153 us; speedup vs baseline: 1.3521x; 1.3521x over previous
//
#include <hip/hip_runtime.h>

// StandGCN2: 2-layer GCN, N=100000, E=600000, 128->128(relu)->64, bf16 I/O.
// Dtype-adaptive (probe sets mode: 0=bf16, 1=fp32); x decode fused into GEMM1.
// Aggregations use batched index prefetch + shfl broadcast + unroll-4 gathers
// to break the per-edge dependent-load chain (R2: 1.6k cyc/edge, latency-bound).

typedef unsigned short u16;
typedef unsigned int u32;
typedef __attribute__((ext_vector_type(8))) short bf16x8;
typedef __attribute__((ext_vector_type(4))) float f32x4;

__device__ __forceinline__ float b2f(u16 s) {
  return __uint_as_float(((u32)s) << 16);
}
__device__ __forceinline__ u16 f2b(float f) {
  u32 u = __float_as_uint(f);
  u32 r = (u + 0x7FFFu + ((u >> 16) & 1u)) >> 16;
  return (u16)r;
}

// ---------------- dtype probe (bf16 exponents cluster in [100,130]) ----------------

__global__ __launch_bounds__(256) void probe_k(const u16* __restrict__ w,
                                               int* __restrict__ mode, int nu16) {
  __shared__ int cnt_s;
  if (threadIdx.x == 0) cnt_s = 0;
  __syncthreads();
  int c = 0;
  for (int i = threadIdx.x; i < nu16; i += 256) {
    u32 e = (w[i] >> 7) & 0xFFu;
    if (e >= 100u && e <= 130u) c++;
  }
  atomicAdd(&cnt_s, c);
  __syncthreads();
  if (threadIdx.x == 0) *mode = (cnt_s < (nu16 * 13) / 16) ? 1 : 0;  // 1 = fp32
}

// Convert all weights/biases in one dispatch: [W1:16384][b1:128][W2:8192][b2:64]
__global__ __launch_bounds__(256) void cvtw_k(const void* W1, const void* b1,
                                              const void* W2, const void* b2,
                                              u16* __restrict__ o1, u16* __restrict__ ob1,
                                              u16* __restrict__ o2, u16* __restrict__ ob2,
                                              const int* __restrict__ mode) {
  int m = *mode;
  int i = blockIdx.x * 256 + threadIdx.x;
  const void* src;
  u16* dst;
  int j = i;
  if (j < 16384)            { src = W1; dst = o1; }
  else if ((j -= 16384) < 128)  { src = b1; dst = ob1; }
  else if ((j -= 128) < 8192)   { src = W2; dst = o2; }
  else if ((j -= 8192) < 64)    { src = b2; dst = ob2; }
  else return;
  dst[j] = m ? f2b(((const float*)src)[j]) : ((const u16*)src)[j];
}

// ---------------- CSR build ----------------

__global__ __launch_bounds__(256) void count_k(const int* __restrict__ dst,
                                               int* __restrict__ cnt, int E) {
  int e = blockIdx.x * 256 + threadIdx.x;
  if (e < E) atomicAdd(&cnt[dst[e]], 1);
}

__global__ __launch_bounds__(256) void scan1(const int* __restrict__ cnt,
                                             int* __restrict__ offs,
                                             int* __restrict__ bsum, int np) {
  __shared__ int lds[256];
  int t = threadIdx.x;
  int i = blockIdx.x * 256 + t;
  int v = cnt[i];
  lds[t] = v;
  __syncthreads();
#pragma unroll
  for (int off = 1; off < 256; off <<= 1) {
    int add = (t >= off) ? lds[t - off] : 0;
    __syncthreads();
    lds[t] += add;
    __syncthreads();
  }
  offs[i] = lds[t] - v;
  if (t == 0) bsum[blockIdx.x] = lds[255];
}

__global__ __launch_bounds__(512) void scan2(const int* __restrict__ bsum,
                                             int* __restrict__ bscan, int nb) {
  __shared__ int lds[512];
  int t = threadIdx.x;
  int v = (t < nb) ? bsum[t] : 0;
  lds[t] = v;
  __syncthreads();
#pragma unroll
  for (int off = 1; off < 512; off <<= 1) {
    int add = (t >= off) ? lds[t - off] : 0;
    __syncthreads();
    lds[t] += add;
    __syncthreads();
  }
  bscan[t] = lds[t] - v;
}

// finalize offsets, init cursor, and compute dinv (fused)
__global__ __launch_bounds__(256) void scan3(int* __restrict__ offs,
                                             const int* __restrict__ bscan,
                                             int* __restrict__ cursor,
                                             const int* __restrict__ cnt,
                                             float* __restrict__ dinv, int np) {
  int i = blockIdx.x * 256 + threadIdx.x;
  int o = offs[i] + bscan[blockIdx.x];
  offs[i] = o;
  cursor[i] = o;
  dinv[i] = rsqrtf((float)cnt[i] + 1.0f);  // +1 self-loop
}

__global__ __launch_bounds__(256) void fill_k(const int* __restrict__ src,
                                              const int* __restrict__ dst,
                                              int* __restrict__ cursor,
                                              int* __restrict__ srcs_sorted, int E) {
  int e = blockIdx.x * 256 + threadIdx.x;
  if (e < E) {
    int p = atomicAdd(&cursor[dst[e]], 1);
    srcs_sorted[p] = src[e];
  }
}

// ---------------- GEMM (bf16 MFMA), K=128, NCOLS in {128,64} ----------------
// CVT=true: A may be fp32 (per *mode), converted during LDS staging.
// Layouts (m89/m91): A[m=lane&15][k=(lane>>4)*8+j], C/D col=lane&15 row=(lane>>4)*4+reg.

template <int NCOLS, bool CVT>
__global__ __launch_bounds__(256) void gemm_k(const void* __restrict__ Araw,
                                              const u16* __restrict__ W,
                                              u16* __restrict__ out, int M,
                                              const int* __restrict__ mode) {
  constexpr int NT = NCOLS / 16;
  __shared__ __align__(16) u16 Wt[NCOLS * 136];
  __shared__ __align__(16) u16 As[64 * 136];
  const int tid = threadIdx.x;
  int mcv = 0;
  if (CVT) mcv = *mode;

  for (int idx = tid; idx < 128 * NCOLS; idx += 256) {
    int n = idx % NCOLS;
    int k = idx / NCOLS;
    Wt[n * 136 + k] = W[k * NCOLS + n];
  }
  __syncthreads();

  const int wv = tid >> 6, lane = tid & 63, lr = lane & 15, lq = lane >> 4;
  const int ntiles = (M + 63) >> 6;

  for (int t = blockIdx.x; t < ntiles; t += gridDim.x) {
    const int r0 = t * 64;
    __syncthreads();
    for (int idx = tid; idx < 64 * 16; idx += 256) {
      int row = idx >> 4, c = idx & 15;
      uint4 v = make_uint4(0u, 0u, 0u, 0u);
      if (r0 + row < M) {
        if (CVT && mcv) {
          const float* xf = (const float*)Araw + (size_t)(r0 + row) * 128 + c * 8;
          float4 f0 = *(const float4*)xf;
          float4 f1 = *(const float4*)(xf + 4);
          v.x = (u32)f2b(f0.x) | ((u32)f2b(f0.y) << 16);
          v.y = (u32)f2b(f0.z) | ((u32)f2b(f0.w) << 16);
          v.z = (u32)f2b(f1.x) | ((u32)f2b(f1.y) << 16);
          v.w = (u32)f2b(f1.z) | ((u32)f2b(f1.w) << 16);
        } else {
          v = *(const uint4*)((const u16*)Araw + (size_t)(r0 + row) * 128 + c * 8);
        }
      }
      *(uint4*)&As[row * 136 + c * 8] = v;
    }
    __syncthreads();

    bf16x8 a[4];
#pragma unroll
    for (int s = 0; s < 4; ++s)
      a[s] = *(const bf16x8*)&As[(wv * 16 + lr) * 136 + s * 32 + lq * 8];

#pragma unroll
    for (int nt = 0; nt < NT; ++nt) {
      f32x4 acc = {0.f, 0.f, 0.f, 0.f};
#pragma unroll
      for (int s = 0; s < 4; ++s) {
        bf16x8 b = *(const bf16x8*)&Wt[(nt * 16 + lr) * 136 + s * 32 + lq * 8];
        acc = __builtin_amdgcn_mfma_f32_16x16x32_bf16(a[s], b, acc, 0, 0, 0);
      }
#pragma unroll
      for (int r = 0; r < 4; ++r) {
        int row = r0 + wv * 16 + lq * 4 + r;
        if (row < M) out[(size_t)row * NCOLS + nt * 16 + lr] = f2b(acc[r]);
      }
    }
  }
}

// ---------------- Aggregation ----------------
// agg1: 128 feats, one wave/node, lane = feature pair. Batched index prefetch:
// lane l loads srcs[start+l] & dinv (independent), shfl-broadcast, unroll-4
// h-gathers. Lanes >= m hold sidx=0, dsv=0 -> zero-padded, no tails.

__global__ __launch_bounds__(256) void agg1(const u16* __restrict__ h,
                                            const int* __restrict__ srcs,
                                            const int* __restrict__ offs,
                                            const int* __restrict__ cnt,
                                            const float* __restrict__ dinv,
                                            const u16* __restrict__ b1,
                                            u16* __restrict__ h1, int n) {
  int i = blockIdx.x * 4 + (threadIdx.x >> 6);
  if (i >= n) return;
  int lane = threadIdx.x & 63;
  int f = lane * 2;
  float di = dinv[i];
  int start = offs[i], c = cnt[i];

  u32 sv = *(const u32*)&h[(size_t)i * 128 + f];
  float ax = b2f((u16)(sv & 0xFFFF)) * di;
  float ay = b2f((u16)(sv >> 16)) * di;

  for (int base = 0; base < c; base += 64) {
    int m = min(64, c - base);
    int sidx = 0;
    float dsv = 0.f;
    if (lane < m) {
      sidx = srcs[start + base + lane];
      dsv = dinv[sidx];
    }
    int m4 = (m + 3) & ~3;
    for (int e = 0; e < m4; e += 4) {
      int s0 = __shfl(sidx, e), s1 = __shfl(sidx, e + 1);
      int s2 = __shfl(sidx, e + 2), s3 = __shfl(sidx, e + 3);
      float d0 = __shfl(dsv, e), d1 = __shfl(dsv, e + 1);
      float d2 = __shfl(dsv, e + 2), d3 = __shfl(dsv, e + 3);
      u32 v0 = *(const u32*)&h[(size_t)s0 * 128 + f];
      u32 v1 = *(const u32*)&h[(size_t)s1 * 128 + f];
      u32 v2 = *(const u32*)&h[(size_t)s2 * 128 + f];
      u32 v3 = *(const u32*)&h[(size_t)s3 * 128 + f];
      ax += b2f((u16)(v0 & 0xFFFF)) * d0 + b2f((u16)(v1 & 0xFFFF)) * d1 +
            b2f((u16)(v2 & 0xFFFF)) * d2 + b2f((u16)(v3 & 0xFFFF)) * d3;
      ay += b2f((u16)(v0 >> 16)) * d0 + b2f((u16)(v1 >> 16)) * d1 +
            b2f((u16)(v2 >> 16)) * d2 + b2f((u16)(v3 >> 16)) * d3;
    }
  }
  u32 bv = *(const u32*)&b1[f];
  float o0 = fmaxf(ax * di + b2f((u16)(bv & 0xFFFF)), 0.f);
  float o1 = fmaxf(ay * di + b2f((u16)(bv >> 16)), 0.f);
  *(u32*)&h1[(size_t)i * 128 + f] = (u32)f2b(o0) | ((u32)f2b(o1) << 16);
}

// agg2: 64 feats. Half-wave split: lanes 0-31 (half 0) / 32-63 (half 1) process
// alternating edges at u32 granularity, shfl_xor(32) reduce at the end.

__global__ __launch_bounds__(256) void agg2(const u16* __restrict__ h2,
                                            const int* __restrict__ srcs,
                                            const int* __restrict__ offs,
                                            const int* __restrict__ cnt,
                                            const float* __restrict__ dinv,
                                            const u16* __restrict__ b2,
                                            void* __restrict__ outv, int n,
                                            const int* __restrict__ mode) {
  int i = blockIdx.x * 4 + (threadIdx.x >> 6);
  if (i >= n) return;
  int lane = threadIdx.x & 63;
  int half = lane >> 5;
  int fl = (lane & 31) * 2;
  float di = dinv[i];
  int start = offs[i], c = cnt[i];

  float ax = 0.f, ay = 0.f;
  if (half == 0) {
    u32 sv = *(const u32*)&h2[(size_t)i * 64 + fl];
    ax = b2f((u16)(sv & 0xFFFF)) * di;
    ay = b2f((u16)(sv >> 16)) * di;
  }

  for (int base = 0; base < c; base += 64) {
    int m = min(64, c - base);
    int sidx = 0;
    float dsv = 0.f;
    if (lane < m) {
      sidx = srcs[start + base + lane];
      dsv = dinv[sidx];
    }
    // edges e = eb + half and eb + 2 + half; zero-pad invalid
    for (int eb = 0; eb < m; eb += 4) {
      int e0 = eb + half, e1 = eb + 2 + half;
      int es0 = e0 & 63, es1 = e1 & 63;
      int s0 = __shfl(sidx, es0), s1 = __shfl(sidx, es1);
      float d0 = __shfl(dsv, es0), d1 = __shfl(dsv, es1);
      if (e0 >= m) d0 = 0.f;
      if (e1 >= m) d1 = 0.f;
      u32 v0 = *(const u32*)&h2[(size_t)s0 * 64 + fl];
      u32 v1 = *(const u32*)&h2[(size_t)s1 * 64 + fl];
      ax += b2f((u16)(v0 & 0xFFFF)) * d0 + b2f((u16)(v1 & 0xFFFF)) * d1;
      ay += b2f((u16)(v0 >> 16)) * d0 + b2f((u16)(v1 >> 16)) * d1;
    }
  }
  ax += __shfl_xor(ax, 32);
  ay += __shfl_xor(ay, 32);

  if (half == 0) {
    u32 bv = *(const u32*)&b2[fl];
    float o0 = ax * di + b2f((u16)(bv & 0xFFFF));
    float o1 = ay * di + b2f((u16)(bv >> 16));
    size_t idx = (size_t)i * 64 + fl;
    if (*mode) {
      ((float*)outv)[idx] = o0;
      ((float*)outv)[idx + 1] = o1;
    } else {
      *(u32*)&((u16*)outv)[idx] = (u32)f2b(o0) | ((u32)f2b(o1) << 16);
    }
  }
}

// ---------------- launch ----------------

extern "C" void kernel_launch(void* const* d_in, const int* in_sizes, int n_in,
                              void* d_out, int out_size, void* d_ws, size_t ws_size,
                              hipStream_t stream) {
  const void* x_raw  = d_in[0];
  const int*  ei     = (const int*)d_in[1];
  const void* W1_raw = d_in[2];
  const void* b1_raw = d_in[3];
  const void* W2_raw = d_in[4];
  const void* b2_raw = d_in[5];

  const int N = in_sizes[0] / 128;
  const int E = in_sizes[1] / 2;
  const int* srcA = ei;
  const int* dstA = ei + E;

  const int NP = ((N + 255) / 256) * 256;
  const int NB = NP / 256;

  char* ws = (char*)d_ws;
  size_t off = 0;
  auto alloc = [&](size_t bytes) -> void* {
    void* p = ws + off;
    off = (off + bytes + 255) & ~(size_t)255;
    return p;
  };
  int*   mode   = (int*)alloc(4);
  int*   cnt    = (int*)alloc((size_t)NP * 4);
  float* dinv   = (float*)alloc((size_t)NP * 4);
  int*   offs   = (int*)alloc((size_t)NP * 4);
  int*   cursor = (int*)alloc((size_t)NP * 4);
  int*   bsum   = (int*)alloc(512 * 4);
  int*   bscan  = (int*)alloc(512 * 4);
  int*   srcs   = (int*)alloc((size_t)E * 4);
  u16*   W1b    = (u16*)alloc((size_t)128 * 128 * 2);
  u16*   b1b    = (u16*)alloc(128 * 2);
  u16*   W2b    = (u16*)alloc((size_t)128 * 64 * 2);
  u16*   b2b    = (u16*)alloc(64 * 2);
  u16*   h      = (u16*)alloc((size_t)N * 128 * 2);
  u16*   h1     = (u16*)alloc((size_t)N * 128 * 2);
  u16*   h2     = (u16*)alloc((size_t)N * 64 * 2);

  hipMemsetAsync(cnt, 0, (size_t)NP * 4, stream);

  probe_k<<<1, 256, 0, stream>>>((const u16*)W1_raw, mode, in_sizes[2]);
  cvtw_k<<<(24768 + 255) / 256, 256, 0, stream>>>(W1_raw, b1_raw, W2_raw, b2_raw,
                                                  W1b, b1b, W2b, b2b, mode);

  const int eb = (E + 255) / 256;
  count_k<<<eb, 256, 0, stream>>>(dstA, cnt, E);
  scan1<<<NB, 256, 0, stream>>>(cnt, offs, bsum, NP);
  scan2<<<1, 512, 0, stream>>>(bsum, bscan, NB);
  scan3<<<NB, 256, 0, stream>>>(offs, bscan, cursor, cnt, dinv, NP);
  fill_k<<<eb, 256, 0, stream>>>(srcA, dstA, cursor, srcs, E);

  gemm_k<128, true><<<512, 256, 0, stream>>>(x_raw, W1b, h, N, mode);
  agg1<<<(N + 3) / 4, 256, 0, stream>>>(h, srcs, offs, cnt, dinv, b1b, h1, N);
  gemm_k<64, false><<<512, 256, 0, stream>>>(h1, W2b, h2, N, mode);
  agg2<<<(N + 3) / 4, 256, 0, stream>>>(h2, srcs, offs, cnt, dinv, b2b, d_out, N, mode);
}

// Round 4
// 253.450 us; speedup vs baseline: 1.4678x; 1.0856x over previous
//
#include <hip/hip_runtime.h>

// StandGCN2: 2-layer GCN, N=100000, E=600000, 128->128(relu)->64, bf16 I/O.
// R4: quarter-wave agg1 (4 nodes/wave, 16 lanes x dwordx4 per row) and oct-wave
// agg2 (8 nodes/wave); per-edge {src,dinv} pairs built in fill_k; per-node
// {start,cnt,dinv} int4 built in scan3 -> 3-stage dependent chain in agg.

typedef unsigned short u16;
typedef unsigned int u32;
typedef __attribute__((ext_vector_type(8))) short bf16x8;
typedef __attribute__((ext_vector_type(4))) float f32x4;

__device__ __forceinline__ float b2f(u16 s) {
  return __uint_as_float(((u32)s) << 16);
}
__device__ __forceinline__ u16 f2b(float f) {
  u32 u = __float_as_uint(f);
  u32 r = (u + 0x7FFFu + ((u >> 16) & 1u)) >> 16;
  return (u16)r;
}
__device__ __forceinline__ u32 pk2(float a, float b) {
  return (u32)f2b(a) | ((u32)f2b(b) << 16);
}
// 8 bf16 (uint4) * d accumulated into acc[8]; lo half = <<16, hi half = &FFFF0000
__device__ __forceinline__ void fma8(uint4 v, float d, float acc[8]) {
  acc[0] = fmaf(__uint_as_float(v.x << 16), d, acc[0]);
  acc[1] = fmaf(__uint_as_float(v.x & 0xFFFF0000u), d, acc[1]);
  acc[2] = fmaf(__uint_as_float(v.y << 16), d, acc[2]);
  acc[3] = fmaf(__uint_as_float(v.y & 0xFFFF0000u), d, acc[3]);
  acc[4] = fmaf(__uint_as_float(v.z << 16), d, acc[4]);
  acc[5] = fmaf(__uint_as_float(v.z & 0xFFFF0000u), d, acc[5]);
  acc[6] = fmaf(__uint_as_float(v.w << 16), d, acc[6]);
  acc[7] = fmaf(__uint_as_float(v.w & 0xFFFF0000u), d, acc[7]);
}
__device__ __forceinline__ void dec8(uint4 v, float f[8]) {
  f[0] = __uint_as_float(v.x << 16);
  f[1] = __uint_as_float(v.x & 0xFFFF0000u);
  f[2] = __uint_as_float(v.y << 16);
  f[3] = __uint_as_float(v.y & 0xFFFF0000u);
  f[4] = __uint_as_float(v.z << 16);
  f[5] = __uint_as_float(v.z & 0xFFFF0000u);
  f[6] = __uint_as_float(v.w << 16);
  f[7] = __uint_as_float(v.w & 0xFFFF0000u);
}

// ---------------- dtype probe (bf16 exponents cluster in [100,130]) ----------------

__global__ __launch_bounds__(256) void probe_k(const u16* __restrict__ w,
                                               int* __restrict__ mode, int nu16) {
  __shared__ int cnt_s;
  if (threadIdx.x == 0) cnt_s = 0;
  __syncthreads();
  int c = 0;
  for (int i = threadIdx.x; i < nu16; i += 256) {
    u32 e = (w[i] >> 7) & 0xFFu;
    if (e >= 100u && e <= 130u) c++;
  }
  atomicAdd(&cnt_s, c);
  __syncthreads();
  if (threadIdx.x == 0) *mode = (cnt_s < (nu16 * 13) / 16) ? 1 : 0;  // 1 = fp32
}

__global__ __launch_bounds__(256) void cvtw_k(const void* W1, const void* b1,
                                              const void* W2, const void* b2,
                                              u16* __restrict__ o1, u16* __restrict__ ob1,
                                              u16* __restrict__ o2, u16* __restrict__ ob2,
                                              const int* __restrict__ mode) {
  int m = *mode;
  int i = blockIdx.x * 256 + threadIdx.x;
  const void* src;
  u16* dst;
  int j = i;
  if (j < 16384)                { src = W1; dst = o1; }
  else if ((j -= 16384) < 128)  { src = b1; dst = ob1; }
  else if ((j -= 128) < 8192)   { src = W2; dst = o2; }
  else if ((j -= 8192) < 64)    { src = b2; dst = ob2; }
  else return;
  dst[j] = m ? f2b(((const float*)src)[j]) : ((const u16*)src)[j];
}

// ---------------- CSR build ----------------

__global__ __launch_bounds__(256) void count_k(const int* __restrict__ dst,
                                               int* __restrict__ cnt, int E) {
  int e = blockIdx.x * 256 + threadIdx.x;
  if (e < E) atomicAdd(&cnt[dst[e]], 1);
}

__global__ __launch_bounds__(256) void scan1(const int* __restrict__ cnt,
                                             int* __restrict__ offs,
                                             int* __restrict__ bsum, int np) {
  __shared__ int lds[256];
  int t = threadIdx.x;
  int i = blockIdx.x * 256 + t;
  int v = cnt[i];
  lds[t] = v;
  __syncthreads();
#pragma unroll
  for (int off = 1; off < 256; off <<= 1) {
    int add = (t >= off) ? lds[t - off] : 0;
    __syncthreads();
    lds[t] += add;
    __syncthreads();
  }
  offs[i] = lds[t] - v;
  if (t == 0) bsum[blockIdx.x] = lds[255];
}

__global__ __launch_bounds__(512) void scan2(const int* __restrict__ bsum,
                                             int* __restrict__ bscan, int nb) {
  __shared__ int lds[512];
  int t = threadIdx.x;
  int v = (t < nb) ? bsum[t] : 0;
  lds[t] = v;
  __syncthreads();
#pragma unroll
  for (int off = 1; off < 512; off <<= 1) {
    int add = (t >= off) ? lds[t - off] : 0;
    __syncthreads();
    lds[t] += add;
    __syncthreads();
  }
  bscan[t] = lds[t] - v;
}

// finalize: cursor, dinv, and packed per-node info {start, cnt, dinv_bits, 0}
__global__ __launch_bounds__(256) void scan3(const int* __restrict__ offs,
                                             const int* __restrict__ bscan,
                                             int* __restrict__ cursor,
                                             const int* __restrict__ cnt,
                                             float* __restrict__ dinv,
                                             int4* __restrict__ ninfo, int np) {
  int i = blockIdx.x * 256 + threadIdx.x;
  int o = offs[i] + bscan[blockIdx.x];
  cursor[i] = o;
  int c = cnt[i];
  float dv = rsqrtf((float)c + 1.0f);  // +1 self-loop
  dinv[i] = dv;
  ninfo[i] = make_int4(o, c, __float_as_int(dv), 0);
}

// per-edge pair {src, dinv[src] bits}
__global__ __launch_bounds__(256) void fill_k(const int* __restrict__ src,
                                              const int* __restrict__ dst,
                                              int* __restrict__ cursor,
                                              const float* __restrict__ dinv,
                                              int2* __restrict__ sp, int E) {
  int e = blockIdx.x * 256 + threadIdx.x;
  if (e < E) {
    int s = src[e];
    float ds = dinv[s];
    int p = atomicAdd(&cursor[dst[e]], 1);
    sp[p] = make_int2(s, __float_as_int(ds));
  }
}

// ---------------- GEMM (bf16 MFMA), K=128, NCOLS in {128,64} ----------------

template <int NCOLS, bool CVT>
__global__ __launch_bounds__(256) void gemm_k(const void* __restrict__ Araw,
                                              const u16* __restrict__ W,
                                              u16* __restrict__ out, int M,
                                              const int* __restrict__ mode) {
  constexpr int NT = NCOLS / 16;
  __shared__ __align__(16) u16 Wt[NCOLS * 136];
  __shared__ __align__(16) u16 As[64 * 136];
  const int tid = threadIdx.x;
  int mcv = 0;
  if (CVT) mcv = *mode;

  for (int idx = tid; idx < 128 * NCOLS; idx += 256) {
    int n = idx % NCOLS;
    int k = idx / NCOLS;
    Wt[n * 136 + k] = W[k * NCOLS + n];
  }
  __syncthreads();

  const int wv = tid >> 6, lane = tid & 63, lr = lane & 15, lq = lane >> 4;
  const int ntiles = (M + 63) >> 6;

  for (int t = blockIdx.x; t < ntiles; t += gridDim.x) {
    const int r0 = t * 64;
    __syncthreads();
    for (int idx = tid; idx < 64 * 16; idx += 256) {
      int row = idx >> 4, c = idx & 15;
      uint4 v = make_uint4(0u, 0u, 0u, 0u);
      if (r0 + row < M) {
        if (CVT && mcv) {
          const float* xf = (const float*)Araw + (size_t)(r0 + row) * 128 + c * 8;
          float4 f0 = *(const float4*)xf;
          float4 f1 = *(const float4*)(xf + 4);
          v.x = (u32)f2b(f0.x) | ((u32)f2b(f0.y) << 16);
          v.y = (u32)f2b(f0.z) | ((u32)f2b(f0.w) << 16);
          v.z = (u32)f2b(f1.x) | ((u32)f2b(f1.y) << 16);
          v.w = (u32)f2b(f1.z) | ((u32)f2b(f1.w) << 16);
        } else {
          v = *(const uint4*)((const u16*)Araw + (size_t)(r0 + row) * 128 + c * 8);
        }
      }
      *(uint4*)&As[row * 136 + c * 8] = v;
    }
    __syncthreads();

    bf16x8 a[4];
#pragma unroll
    for (int s = 0; s < 4; ++s)
      a[s] = *(const bf16x8*)&As[(wv * 16 + lr) * 136 + s * 32 + lq * 8];

#pragma unroll
    for (int nt = 0; nt < NT; ++nt) {
      f32x4 acc = {0.f, 0.f, 0.f, 0.f};
#pragma unroll
      for (int s = 0; s < 4; ++s) {
        bf16x8 b = *(const bf16x8*)&Wt[(nt * 16 + lr) * 136 + s * 32 + lq * 8];
        acc = __builtin_amdgcn_mfma_f32_16x16x32_bf16(a[s], b, acc, 0, 0, 0);
      }
#pragma unroll
      for (int r = 0; r < 4; ++r) {
        int row = r0 + wv * 16 + lq * 4 + r;
        if (row < M) out[(size_t)row * NCOLS + nt * 16 + lr] = f2b(acc[r]);
      }
    }
  }
}

// ---------------- agg1: quarter-wave, 4 nodes/wave, 16 nodes/block ----------------

__global__ __launch_bounds__(256) void agg1(const u16* __restrict__ h,
                                            const int2* __restrict__ sp,
                                            const int4* __restrict__ ninfo,
                                            const u16* __restrict__ b1,
                                            u16* __restrict__ h1, int n) {
  const int lane = threadIdx.x & 63;
  const int q = lane >> 4, l16 = lane & 15;
  const int i = blockIdx.x * 16 + (threadIdx.x >> 6) * 4 + q;
  const bool valid = (i < n);

  int start = 0, c = 0;
  float di = 0.f;
  if (valid) {
    int4 ni = ninfo[i];
    start = ni.x;
    c = ni.y;
    di = __int_as_float(ni.z);
  }

  float acc[8];
  {
    uint4 v = valid ? *(const uint4*)(h + (size_t)i * 128 + l16 * 8)
                    : make_uint4(0u, 0u, 0u, 0u);
    float f[8];
    dec8(v, f);
#pragma unroll
    for (int j = 0; j < 8; ++j) acc[j] = f[j] * di;
  }

  const int bl = q * 16;
  for (int base = 0; __any(base < c); base += 16) {
    int m = c - base;
    m = m < 0 ? 0 : (m > 16 ? 16 : m);
    int s = 0;
    int db = 0;
    if (l16 < m) {
      int2 p = sp[start + base + l16];
      s = p.x;
      db = p.y;
    }
    int mmw = m;
    mmw = max(mmw, __shfl_xor(mmw, 16));
    mmw = max(mmw, __shfl_xor(mmw, 32));
    for (int e = 0; e < mmw; e += 2) {
      int s0 = __shfl(s, bl + e);
      int s1 = __shfl(s, bl + e + 1);
      float d0 = __int_as_float(__shfl(db, bl + e));
      float d1 = __int_as_float(__shfl(db, bl + e + 1));
      uint4 v0 = *(const uint4*)(h + (size_t)s0 * 128 + l16 * 8);
      uint4 v1 = *(const uint4*)(h + (size_t)s1 * 128 + l16 * 8);
      fma8(v0, d0, acc);
      fma8(v1, d1, acc);
    }
  }

  if (valid) {
    uint4 bv = *(const uint4*)(b1 + l16 * 8);
    float bf[8];
    dec8(bv, bf);
    float o[8];
#pragma unroll
    for (int j = 0; j < 8; ++j) o[j] = fmaxf(fmaf(acc[j], di, bf[j]), 0.f);
    uint4 ov;
    ov.x = pk2(o[0], o[1]);
    ov.y = pk2(o[2], o[3]);
    ov.z = pk2(o[4], o[5]);
    ov.w = pk2(o[6], o[7]);
    *(uint4*)(h1 + (size_t)i * 128 + l16 * 8) = ov;
  }
}

// ---------------- agg2: oct-wave, 8 nodes/wave, 32 nodes/block ----------------

__global__ __launch_bounds__(256) void agg2(const u16* __restrict__ h2,
                                            const int2* __restrict__ sp,
                                            const int4* __restrict__ ninfo,
                                            const u16* __restrict__ b2,
                                            void* __restrict__ outv, int n,
                                            const int* __restrict__ mode) {
  const int lane = threadIdx.x & 63;
  const int o8 = lane >> 3, l8 = lane & 7;
  const int i = blockIdx.x * 32 + (threadIdx.x >> 6) * 8 + o8;
  const bool valid = (i < n);

  int start = 0, c = 0;
  float di = 0.f;
  if (valid) {
    int4 ni = ninfo[i];
    start = ni.x;
    c = ni.y;
    di = __int_as_float(ni.z);
  }

  float acc[8];
  {
    uint4 v = valid ? *(const uint4*)(h2 + (size_t)i * 64 + l8 * 8)
                    : make_uint4(0u, 0u, 0u, 0u);
    float f[8];
    dec8(v, f);
#pragma unroll
    for (int j = 0; j < 8; ++j) acc[j] = f[j] * di;
  }

  const int bl = o8 * 8;
  for (int base = 0; __any(base < c); base += 8) {
    int m = c - base;
    m = m < 0 ? 0 : (m > 8 ? 8 : m);
    int s = 0;
    int db = 0;
    if (l8 < m) {
      int2 p = sp[start + base + l8];
      s = p.x;
      db = p.y;
    }
    int mmw = m;
    mmw = max(mmw, __shfl_xor(mmw, 8));
    mmw = max(mmw, __shfl_xor(mmw, 16));
    mmw = max(mmw, __shfl_xor(mmw, 32));
    for (int e = 0; e < mmw; e += 2) {
      int s0 = __shfl(s, bl + e);
      int s1 = __shfl(s, bl + e + 1);
      float d0 = __int_as_float(__shfl(db, bl + e));
      float d1 = __int_as_float(__shfl(db, bl + e + 1));
      uint4 v0 = *(const uint4*)(h2 + (size_t)s0 * 64 + l8 * 8);
      uint4 v1 = *(const uint4*)(h2 + (size_t)s1 * 64 + l8 * 8);
      fma8(v0, d0, acc);
      fma8(v1, d1, acc);
    }
  }

  if (valid) {
    uint4 bv = *(const uint4*)(b2 + l8 * 8);
    float bf[8];
    dec8(bv, bf);
    float o[8];
#pragma unroll
    for (int j = 0; j < 8; ++j) o[j] = fmaf(acc[j], di, bf[j]);
    if (*mode) {
      float* op = (float*)outv + (size_t)i * 64 + l8 * 8;
      *(float4*)op = make_float4(o[0], o[1], o[2], o[3]);
      *(float4*)(op + 4) = make_float4(o[4], o[5], o[6], o[7]);
    } else {
      uint4 ov;
      ov.x = pk2(o[0], o[1]);
      ov.y = pk2(o[2], o[3]);
      ov.z = pk2(o[4], o[5]);
      ov.w = pk2(o[6], o[7]);
      *(uint4*)((u16*)outv + (size_t)i * 64 + l8 * 8) = ov;
    }
  }
}

// ---------------- launch ----------------

extern "C" void kernel_launch(void* const* d_in, const int* in_sizes, int n_in,
                              void* d_out, int out_size, void* d_ws, size_t ws_size,
                              hipStream_t stream) {
  const void* x_raw  = d_in[0];
  const int*  ei     = (const int*)d_in[1];
  const void* W1_raw = d_in[2];
  const void* b1_raw = d_in[3];
  const void* W2_raw = d_in[4];
  const void* b2_raw = d_in[5];

  const int N = in_sizes[0] / 128;
  const int E = in_sizes[1] / 2;
  const int* srcA = ei;
  const int* dstA = ei + E;

  const int NP = ((N + 255) / 256) * 256;
  const int NB = NP / 256;

  char* ws = (char*)d_ws;
  size_t off = 0;
  auto alloc = [&](size_t bytes) -> void* {
    void* p = ws + off;
    off = (off + bytes + 255) & ~(size_t)255;
    return p;
  };
  int*   mode   = (int*)alloc(4);
  int*   cnt    = (int*)alloc((size_t)NP * 4);
  float* dinv   = (float*)alloc((size_t)NP * 4);
  int*   offs   = (int*)alloc((size_t)NP * 4);
  int*   cursor = (int*)alloc((size_t)NP * 4);
  int*   bsum   = (int*)alloc(512 * 4);
  int*   bscan  = (int*)alloc(512 * 4);
  int4*  ninfo  = (int4*)alloc((size_t)NP * 16);
  int2*  sp     = (int2*)alloc((size_t)E * 8);
  u16*   W1b    = (u16*)alloc((size_t)128 * 128 * 2);
  u16*   b1b    = (u16*)alloc(128 * 2);
  u16*   W2b    = (u16*)alloc((size_t)128 * 64 * 2);
  u16*   b2b    = (u16*)alloc(64 * 2);
  u16*   h      = (u16*)alloc((size_t)N * 128 * 2);
  u16*   h1     = (u16*)alloc((size_t)N * 128 * 2);
  u16*   h2     = (u16*)alloc((size_t)N * 64 * 2);

  hipMemsetAsync(cnt, 0, (size_t)NP * 4, stream);

  probe_k<<<1, 256, 0, stream>>>((const u16*)W1_raw, mode, in_sizes[2]);
  cvtw_k<<<(24768 + 255) / 256, 256, 0, stream>>>(W1_raw, b1_raw, W2_raw, b2_raw,
                                                  W1b, b1b, W2b, b2b, mode);

  const int eb = (E + 255) / 256;
  count_k<<<eb, 256, 0, stream>>>(dstA, cnt, E);
  scan1<<<NB, 256, 0, stream>>>(cnt, offs, bsum, NP);
  scan2<<<1, 512, 0, stream>>>(bsum, bscan, NB);
  scan3<<<NB, 256, 0, stream>>>(offs, bscan, cursor, cnt, dinv, ninfo, NP);
  fill_k<<<eb, 256, 0, stream>>>(srcA, dstA, cursor, dinv, sp, E);

  gemm_k<128, true><<<1024, 256, 0, stream>>>(x_raw, W1b, h, N, mode);
  agg1<<<(N + 15) / 16, 256, 0, stream>>>(h, sp, ninfo, b1b, h1, N);
  gemm_k<64, false><<<512, 256, 0, stream>>>(h1, W2b, h2, N, mode);
  agg2<<<(N + 31) / 32, 256, 0, stream>>>(h2, sp, ninfo, b2b, d_out, N, mode);
}